// Round 6
// baseline (155.468 us; speedup 1.0000x reference)
//
#include <hip/hip_runtime.h>
#include <hip/hip_bf16.h>
#include <math.h>

#define DMODEL 512
#define T_SEQ 2048
#define NH 8
#define DH 64
#define M_ROWS 4096
#define LDST 72   // padded LDS row stride (retention kernels only)

typedef short s16x8 __attribute__((ext_vector_type(8)));
typedef float f32x4 __attribute__((ext_vector_type(4)));
typedef unsigned short u16x4 __attribute__((ext_vector_type(4)));

static __device__ __forceinline__ unsigned short f2bf(float f) {
  __hip_bfloat16 h = __float2bfloat16(f);
  return *(unsigned short*)&h;
}
static __device__ __forceinline__ float bf2f(unsigned short u) {
  union { unsigned int i; float f; } x; x.i = (unsigned int)u << 16; return x.f;
}
// async global->LDS 16B copy; LDS dest must be wave-uniform base + lane*16
static __device__ __forceinline__ void gld16(void* lds, const void* g) {
  __builtin_amdgcn_global_load_lds(
      (const __attribute__((address_space(1))) unsigned int*)g,
      (__attribute__((address_space(3))) unsigned int*)lds, 16, 0, 0);
}

// ---------------------------------------------------------------------------
// Fused prep: blocks 0..1023 cast x -> bf16; blocks 1024..1343 transpose+cast
// the 5 weight matrices: WT[z*512 + n][k] = W_z[k][n].
// ---------------------------------------------------------------------------
__global__ __launch_bounds__(256) void prep_k(
    const float* __restrict__ x, unsigned short* __restrict__ Xb,
    const float* __restrict__ W0, const float* __restrict__ W1,
    const float* __restrict__ W2, const float* __restrict__ W3,
    const float* __restrict__ W4, unsigned short* __restrict__ WT)
{
  __shared__ __align__(16) unsigned short buf[64 * LDST];
  const int bid = blockIdx.x, tid = threadIdx.x;
  if (bid < 1024) {
    const size_t i = ((size_t)bid * 256 + tid) * 8;
    float4 a = *(const float4*)&x[i];
    float4 b = *(const float4*)&x[i + 4];
    s16x8 o;
    o[0]=f2bf(a.x); o[1]=f2bf(a.y); o[2]=f2bf(a.z); o[3]=f2bf(a.w);
    o[4]=f2bf(b.x); o[5]=f2bf(b.y); o[6]=f2bf(b.z); o[7]=f2bf(b.w);
    *(s16x8*)&Xb[i] = o;
    return;
  }
  const int bid2 = bid - 1024;
  const int z = bid2 >> 6, rem = bid2 & 63;
  const int n0 = (rem & 7) * 64, k0 = (rem >> 3) * 64;
  const float* W = (z==0)?W0:(z==1)?W1:(z==2)?W2:(z==3)?W3:W4;
  #pragma unroll
  for (int r = 0; r < 4; ++r) {
    int idx = r * 256 + tid;
    int kr = idx >> 4, nc = idx & 15;
    float4 v = *(const float4*)&W[(size_t)(k0 + kr) * DMODEL + n0 + nc * 4];
    buf[(nc*4+0) * LDST + kr] = f2bf(v.x);
    buf[(nc*4+1) * LDST + kr] = f2bf(v.y);
    buf[(nc*4+2) * LDST + kr] = f2bf(v.z);
    buf[(nc*4+3) * LDST + kr] = f2bf(v.w);
  }
  __syncthreads();
  #pragma unroll
  for (int r = 0; r < 2; ++r) {
    int idx = r * 256 + tid;
    int nr = idx >> 3, c = idx & 7;
    *(s16x8*)&WT[((size_t)z * DMODEL + n0 + nr) * DMODEL + k0 + c * 8] =
        *(const s16x8*)&buf[nr * LDST + c * 8];
  }
}

// ---------------------------------------------------------------------------
// Projection GEMM: C = A(4096x512 bf16) @ BT^T, 128x128 tile, BK=64.
// m97-style global_load_lds + XOR chunk swizzle. All outputs bf16.
// ---------------------------------------------------------------------------
__global__ __launch_bounds__(256) void mfma_gemm_k(
    const unsigned short* __restrict__ A, const unsigned short* __restrict__ BT,
    unsigned short* __restrict__ C0, unsigned short* __restrict__ C1,
    unsigned short* __restrict__ C2, unsigned short* __restrict__ C3)
{
  __shared__ __align__(16) unsigned short As[128 * 64];
  __shared__ __align__(16) unsigned short Bs[128 * 64];
  const int ng0 = blockIdx.x * 128;
  const int m0 = blockIdx.y * 128;
  const int z = ng0 >> 9, n0 = ng0 & 511;
  unsigned short* Cz = (z==0)?C0:(z==1)?C1:(z==2)?C2:C3;
  const int tid = threadIdx.x;
  const int wave = tid >> 6, lane = tid & 63;
  const int wm = wave >> 1, wn = wave & 1;
  const int n = lane & 15, quad = lane >> 4;

  int srow[4], scol[4];
  #pragma unroll
  for (int r = 0; r < 4; ++r) {
    int idx = r * 256 + tid;
    srow[r] = idx >> 3;
    scol[r] = ((idx & 7) ^ (srow[r] & 7)) * 8;
  }

  f32x4 acc[4][4];
  #pragma unroll
  for (int mi = 0; mi < 4; ++mi)
    #pragma unroll
    for (int ni = 0; ni < 4; ++ni) acc[mi][ni] = (f32x4){0.f,0.f,0.f,0.f};

  for (int k0 = 0; k0 < 512; k0 += 64) {
    #pragma unroll
    for (int r = 0; r < 4; ++r) {
      int idx = r * 256 + tid;
      gld16(&As[idx * 8], &A[(size_t)(m0 + srow[r]) * DMODEL + k0 + scol[r]]);
      gld16(&Bs[idx * 8], &BT[(size_t)(ng0 + srow[r]) * DMODEL + k0 + scol[r]]);
    }
    __syncthreads();
    #pragma unroll
    for (int kk = 0; kk < 2; ++kk) {
      s16x8 af[4], bf[4];
      #pragma unroll
      for (int mi = 0; mi < 4; ++mi) {
        int R = wm*64 + mi*16 + n, cc = (kk*4 + quad) ^ (n & 7);
        af[mi] = *(const s16x8*)&As[R * 64 + cc * 8];
      }
      #pragma unroll
      for (int ni = 0; ni < 4; ++ni) {
        int R = wn*64 + ni*16 + n, cc = (kk*4 + quad) ^ (n & 7);
        bf[ni] = *(const s16x8*)&Bs[R * 64 + cc * 8];
      }
      #pragma unroll
      for (int mi = 0; mi < 4; ++mi)
        #pragma unroll
        for (int ni = 0; ni < 4; ++ni)
          acc[mi][ni] = __builtin_amdgcn_mfma_f32_16x16x32_bf16(
              af[mi], bf[ni], acc[mi][ni], 0, 0, 0);
    }
    __syncthreads();
  }

  #pragma unroll
  for (int mi = 0; mi < 4; ++mi)
    #pragma unroll
    for (int ni = 0; ni < 4; ++ni)
      #pragma unroll
      for (int r = 0; r < 4; ++r)
        Cz[(size_t)(m0 + wm*64 + mi*16 + quad*4 + r) * DMODEL +
           n0 + wn*64 + ni*16 + n] = f2bf(acc[mi][ni][r]);
}

// ---------------------------------------------------------------------------
// Chunked retention stage 1: AT[bh][c][d2][d1] = sum_m g^(64-m) K[m][d1] V[m][d2]
// ---------------------------------------------------------------------------
__global__ __launch_bounds__(256) void ret_kv_k(
    const unsigned short* __restrict__ Kb, const unsigned short* __restrict__ Vb,
    float* __restrict__ AT)
{
  __shared__ __align__(16) unsigned short Kts[64 * LDST]; // [d1][m], scaled
  __shared__ __align__(16) unsigned short Vts[64 * LDST]; // [d2][m]
  const int c = blockIdx.x, h = blockIdx.y, b = blockIdx.z;
  const int bh = b * NH + h;
  const int tid = threadIdx.x;
  const int wave = tid >> 6, lane = tid & 63;
  const int n = lane & 15, quad = lane >> 4;
  const size_t base = ((size_t)b * T_SEQ + (size_t)c * 64) * DMODEL + h * DH;
  const float lg = log2f(1.0f - exp2f(-5.0f - (float)h));

  #pragma unroll
  for (int r = 0; r < 2; ++r) {
    int idx = r * 256 + tid;
    int m = idx & 63, ch = idx >> 6;
    s16x8 kv = *(const s16x8*)&Kb[base + (size_t)m * DMODEL + ch * 8];
    s16x8 vv = *(const s16x8*)&Vb[base + (size_t)m * DMODEL + ch * 8];
    float sc = exp2f((float)(64 - m) * lg);
    #pragma unroll
    for (int e = 0; e < 8; ++e) {
      Kts[(ch * 8 + e) * LDST + m] = f2bf(bf2f(((unsigned short*)&kv)[e]) * sc);
      Vts[(ch * 8 + e) * LDST + m] = ((unsigned short*)&vv)[e];
    }
  }
  __syncthreads();

  f32x4 at[4];
  #pragma unroll
  for (int j = 0; j < 4; ++j) at[j] = (f32x4){0.f,0.f,0.f,0.f};
  #pragma unroll
  for (int kk = 0; kk < 2; ++kk) {
    s16x8 a = *(const s16x8*)&Vts[(wave*16 + n) * LDST + kk*32 + quad*8];
    #pragma unroll
    for (int j = 0; j < 4; ++j) {
      s16x8 bf = *(const s16x8*)&Kts[(j*16 + n) * LDST + kk*32 + quad*8];
      at[j] = __builtin_amdgcn_mfma_f32_16x16x32_bf16(a, bf, at[j], 0, 0, 0);
    }
  }
  float* Ab = AT + (((size_t)bh * 32 + c) << 12);
  #pragma unroll
  for (int j = 0; j < 4; ++j)
    #pragma unroll
    for (int r = 0; r < 4; ++r)
      Ab[(wave*16 + quad*4 + r) * 64 + j*16 + n] = at[j][r];
}

// ---------------------------------------------------------------------------
// Chunked retention stage 2 (fused scan + output):
//   S_c = Horner prefix of AT over chunks (fp32 regs, 16 elems/thread)
//   O = diag-tile flash + 0.125*g^i*(Q @ S_c)
// ---------------------------------------------------------------------------
__global__ __launch_bounds__(256) void ret_o2_k(
    const unsigned short* __restrict__ Qb, const unsigned short* __restrict__ Kb,
    const unsigned short* __restrict__ Vb, const float* __restrict__ AT,
    float* __restrict__ RET)
{
  __shared__ __align__(16) unsigned short Qs[64 * LDST];
  __shared__ __align__(16) unsigned short Ks[64 * LDST];
  __shared__ __align__(16) unsigned short Vst[64 * LDST]; // [d2][m]
  __shared__ __align__(16) unsigned short Ss[64 * LDST];  // [d2][d1]
  __shared__ __align__(16) unsigned short Ps[64 * LDST];
  const int c = (int)gridDim.x - 1 - (int)blockIdx.x;     // heavy chunks first
  const int h = blockIdx.y, b = blockIdx.z;
  const int bh = b * NH + h;
  const int tid = threadIdx.x;
  const int wave = tid >> 6, lane = tid & 63;
  const int n = lane & 15, quad = lane >> 4;
  const size_t base = ((size_t)b * T_SEQ + (size_t)c * 64) * DMODEL + h * DH;
  const float lg = log2f(1.0f - exp2f(-5.0f - (float)h));
  const float g64 = exp2f(64.0f * lg);

  // stage Q, K, V tiles
  #pragma unroll
  for (int r = 0; r < 2; ++r) {
    int idx = r * 256 + tid;
    int i = idx >> 3, ch = idx & 7;
    *(s16x8*)&Qs[i * LDST + ch * 8] =
        *(const s16x8*)&Qb[base + (size_t)i * DMODEL + ch * 8];
    *(s16x8*)&Ks[i * LDST + ch * 8] =
        *(const s16x8*)&Kb[base + (size_t)i * DMODEL + ch * 8];
  }
  #pragma unroll
  for (int r = 0; r < 2; ++r) {
    int idx = r * 256 + tid;
    int m = idx & 63, ch = idx >> 6;
    s16x8 vv = *(const s16x8*)&Vb[base + (size_t)m * DMODEL + ch * 8];
    #pragma unroll
    for (int e = 0; e < 8; ++e)
      Vst[(ch * 8 + e) * LDST + m] = ((unsigned short*)&vv)[e];
  }

  // Horner prefix state: S_c = sum_{cp<c} g64^(c-1-cp) * A[cp], 16 elems/thread
  const float* Ac = AT + (((size_t)bh * 32) << 12) + (size_t)tid * 16;
  float4 S0 = {0,0,0,0}, S1 = S0, S2 = S0, S3 = S0;
  if (c > 0) {
    float4 n0 = *(const float4*)(Ac + 0);
    float4 n1 = *(const float4*)(Ac + 4);
    float4 n2 = *(const float4*)(Ac + 8);
    float4 n3 = *(const float4*)(Ac + 12);
    for (int cp = 0; cp < c; ++cp) {
      float4 a0 = n0, a1 = n1, a2 = n2, a3 = n3;
      if (cp + 1 < c) {
        const float* p = Ac + ((size_t)(cp + 1) << 12);
        n0 = *(const float4*)(p + 0);  n1 = *(const float4*)(p + 4);
        n2 = *(const float4*)(p + 8);  n3 = *(const float4*)(p + 12);
      }
      S0.x = fmaf(g64, S0.x, a0.x); S0.y = fmaf(g64, S0.y, a0.y);
      S0.z = fmaf(g64, S0.z, a0.z); S0.w = fmaf(g64, S0.w, a0.w);
      S1.x = fmaf(g64, S1.x, a1.x); S1.y = fmaf(g64, S1.y, a1.y);
      S1.z = fmaf(g64, S1.z, a1.z); S1.w = fmaf(g64, S1.w, a1.w);
      S2.x = fmaf(g64, S2.x, a2.x); S2.y = fmaf(g64, S2.y, a2.y);
      S2.z = fmaf(g64, S2.z, a2.z); S2.w = fmaf(g64, S2.w, a2.w);
      S3.x = fmaf(g64, S3.x, a3.x); S3.y = fmaf(g64, S3.y, a3.y);
      S3.z = fmaf(g64, S3.z, a3.z); S3.w = fmaf(g64, S3.w, a3.w);
    }
  }
  // write S_c (bf16) into Ss: thread's elems are row d2 = tid>>2,
  // cols (tid&3)*16 .. +15
  {
    const int d2 = tid >> 2, d1b = (tid & 3) * 16;
    s16x8 lo, hi;
    lo[0]=f2bf(S0.x); lo[1]=f2bf(S0.y); lo[2]=f2bf(S0.z); lo[3]=f2bf(S0.w);
    lo[4]=f2bf(S1.x); lo[5]=f2bf(S1.y); lo[6]=f2bf(S1.z); lo[7]=f2bf(S1.w);
    hi[0]=f2bf(S2.x); hi[1]=f2bf(S2.y); hi[2]=f2bf(S2.z); hi[3]=f2bf(S2.w);
    hi[4]=f2bf(S3.x); hi[5]=f2bf(S3.y); hi[6]=f2bf(S3.z); hi[7]=f2bf(S3.w);
    *(s16x8*)&Ss[d2 * LDST + d1b] = lo;
    *(s16x8*)&Ss[d2 * LDST + d1b + 8] = hi;
  }
  __syncthreads();

  f32x4 s[4], u[4];
  #pragma unroll
  for (int j = 0; j < 4; ++j) {
    s[j] = (f32x4){0.f,0.f,0.f,0.f};
    u[j] = (f32x4){0.f,0.f,0.f,0.f};
  }
  #pragma unroll
  for (int kk = 0; kk < 2; ++kk) {
    s16x8 a = *(const s16x8*)&Qs[(wave*16 + n) * LDST + kk*32 + quad*8];
    #pragma unroll
    for (int j = 0; j < 4; ++j) {
      s16x8 bk = *(const s16x8*)&Ks[(j*16 + n) * LDST + kk*32 + quad*8];
      s[j] = __builtin_amdgcn_mfma_f32_16x16x32_bf16(a, bk, s[j], 0, 0, 0);
      s16x8 bs = *(const s16x8*)&Ss[(j*16 + n) * LDST + kk*32 + quad*8];
      u[j] = __builtin_amdgcn_mfma_f32_16x16x32_bf16(a, bs, u[j], 0, 0, 0);
    }
  }

  float rowf[4], colf[4];
  #pragma unroll
  for (int r = 0; r < 4; ++r) rowf[r] = exp2f((float)(wave*16 + quad*4 + r) * lg);
  #pragma unroll
  for (int j = 0; j < 4; ++j) colf[j] = exp2f(-(float)(j*16 + n) * lg);

  #pragma unroll
  for (int j = 0; j < 4; ++j)
    #pragma unroll
    for (int r = 0; r < 4; ++r) {
      int i = wave*16 + quad*4 + r, mcol = j*16 + n;
      float v = (mcol <= i) ? s[j][r] * 0.125f * rowf[r] * colf[j] : 0.0f;
      Ps[i * LDST + mcol] = f2bf(v);
    }
  __syncthreads();

  f32x4 acc[4];
  #pragma unroll
  for (int j = 0; j < 4; ++j) acc[j] = (f32x4){0.f,0.f,0.f,0.f};
  #pragma unroll
  for (int kk = 0; kk < 2; ++kk) {
    s16x8 a = *(const s16x8*)&Ps[(wave*16 + n) * LDST + kk*32 + quad*8];
    #pragma unroll
    for (int j = 0; j < 4; ++j) {
      s16x8 bf = *(const s16x8*)&Vst[(j*16 + n) * LDST + kk*32 + quad*8];
      acc[j] = __builtin_amdgcn_mfma_f32_16x16x32_bf16(a, bf, acc[j], 0, 0, 0);
    }
  }

  #pragma unroll
  for (int j = 0; j < 4; ++j)
    #pragma unroll
    for (int r = 0; r < 4; ++r) {
      int i = wave*16 + quad*4 + r;
      RET[((size_t)b * T_SEQ + (size_t)c * 64 + i) * DMODEL + h*DH + j*16 + n] =
          acc[j][r] + 0.125f * rowf[r] * u[j][r];
    }
}

// ---------------------------------------------------------------------------
// Output GEMM with fused GroupNorm+SiLU gate on the A side:
//   A[row][k] = silu(G[row][k] + gn(RET[row][group(k)])*gnw + gnb)
// Each BK=64 chunk is exactly one GroupNorm group (HEAD_SIZE=64).
// ---------------------------------------------------------------------------
__global__ __launch_bounds__(256) void out_gemm_k(
    const float* __restrict__ RET, const unsigned short* __restrict__ Gg,
    const float* __restrict__ gnw, const float* __restrict__ gnb,
    const unsigned short* __restrict__ BT, float* __restrict__ out)
{
  __shared__ __align__(16) unsigned short As[128 * 64];
  __shared__ __align__(16) unsigned short Bs[128 * 64];
  const int n0 = blockIdx.x * 128;
  const int m0 = blockIdx.y * 128;
  const int tid = threadIdx.x;
  const int wave = tid >> 6, lane = tid & 63;
  const int wm = wave >> 1, wn = wave & 1;
  const int n = lane & 15, quad = lane >> 4;
  const int arow = tid >> 1, ahalf = tid & 1;   // A staging: row, 32-col half

  int srow[4], scol[4];
  #pragma unroll
  for (int r = 0; r < 4; ++r) {
    int idx = r * 256 + tid;
    srow[r] = idx >> 3;
    scol[r] = ((idx & 7) ^ (srow[r] & 7)) * 8;
  }

  f32x4 acc[4][4];
  #pragma unroll
  for (int mi = 0; mi < 4; ++mi)
    #pragma unroll
    for (int ni = 0; ni < 4; ++ni) acc[mi][ni] = (f32x4){0.f,0.f,0.f,0.f};

  for (int k0 = 0; k0 < 512; k0 += 64) {
    // B tile: async global->LDS, swizzled
    #pragma unroll
    for (int r = 0; r < 4; ++r) {
      int idx = r * 256 + tid;
      gld16(&Bs[idx * 8], &BT[(size_t)(n0 + srow[r]) * DMODEL + k0 + scol[r]]);
    }
    // A tile: fused gn+gate from RET (fp32) and Gg (bf16)
    {
      const float* Rp = &RET[(size_t)(m0 + arow) * DMODEL + k0 + ahalf * 32];
      float vals[32];
      #pragma unroll
      for (int q = 0; q < 8; ++q) {
        float4 v = *(const float4*)(Rp + q * 4);
        vals[q*4+0]=v.x; vals[q*4+1]=v.y; vals[q*4+2]=v.z; vals[q*4+3]=v.w;
      }
      float sum = 0.f, sq = 0.f;
      #pragma unroll
      for (int e = 0; e < 32; ++e) { sum += vals[e]; sq = fmaf(vals[e], vals[e], sq); }
      sum += __shfl_xor(sum, 1);
      sq  += __shfl_xor(sq, 1);
      const float mean = sum * (1.0f / 64.0f);
      float var = sq * (1.0f / 64.0f) - mean * mean;
      var = fmaxf(var, 0.0f);
      const float rstd = rsqrtf(var + 1e-5f);
      const unsigned short* Gp = &Gg[(size_t)(m0 + arow) * DMODEL + k0 + ahalf * 32];
      const float* wp = &gnw[k0 + ahalf * 32];
      const float* bp = &gnb[k0 + ahalf * 32];
      #pragma unroll
      for (int cc = 0; cc < 4; ++cc) {
        s16x8 gv = *(const s16x8*)(Gp + cc * 8);
        s16x8 o;
        #pragma unroll
        for (int e = 0; e < 8; ++e) {
          int col = cc * 8 + e;
          float normed = (vals[col] - mean) * rstd * wp[col] + bp[col];
          float uu = bf2f(((unsigned short*)&gv)[e]) + normed;
          o[e] = f2bf(uu / (1.0f + expf(-uu)));
        }
        int chg = ahalf * 4 + cc;                 // global chunk in row
        *(s16x8*)&As[arow * 64 + (chg ^ (arow & 7)) * 8] = o;
      }
    }
    __syncthreads();
    #pragma unroll
    for (int kk = 0; kk < 2; ++kk) {
      s16x8 af[4], bf[4];
      #pragma unroll
      for (int mi = 0; mi < 4; ++mi) {
        int R = wm*64 + mi*16 + n, cc = (kk*4 + quad) ^ (n & 7);
        af[mi] = *(const s16x8*)&As[R * 64 + cc * 8];
      }
      #pragma unroll
      for (int ni = 0; ni < 4; ++ni) {
        int R = wn*64 + ni*16 + n, cc = (kk*4 + quad) ^ (n & 7);
        bf[ni] = *(const s16x8*)&Bs[R * 64 + cc * 8];
      }
      #pragma unroll
      for (int mi = 0; mi < 4; ++mi)
        #pragma unroll
        for (int ni = 0; ni < 4; ++ni)
          acc[mi][ni] = __builtin_amdgcn_mfma_f32_16x16x32_bf16(
              af[mi], bf[ni], acc[mi][ni], 0, 0, 0);
    }
    __syncthreads();
  }

  #pragma unroll
  for (int mi = 0; mi < 4; ++mi)
    #pragma unroll
    for (int ni = 0; ni < 4; ++ni)
      #pragma unroll
      for (int r = 0; r < 4; ++r)
        out[(size_t)(m0 + wm*64 + mi*16 + quad*4 + r) * DMODEL +
            n0 + wn*64 + ni*16 + n] = acc[mi][ni][r];
}

// ---------------------------------------------------------------------------
extern "C" void kernel_launch(void* const* d_in, const int* in_sizes, int n_in,
                              void* d_out, int out_size, void* d_ws, size_t ws_size,
                              hipStream_t stream) {
  const float* x   = (const float*)d_in[0];
  const float* WQ  = (const float*)d_in[1];
  const float* WK  = (const float*)d_in[2];
  const float* WV  = (const float*)d_in[3];
  const float* WG  = (const float*)d_in[4];
  const float* WO  = (const float*)d_in[5];
  const float* gnw = (const float*)d_in[6];
  const float* gnb = (const float*)d_in[7];
  float* out = (float*)d_out;

  char* ws = (char*)d_ws;
  unsigned short* Xb = (unsigned short*)(ws);                 // 4 MB
  unsigned short* Qb = (unsigned short*)(ws + 4  * (1<<20));  // 4 MB
  unsigned short* Kb = (unsigned short*)(ws + 8  * (1<<20));  // 4 MB
  unsigned short* Vb = (unsigned short*)(ws + 12 * (1<<20));  // 4 MB
  unsigned short* G  = (unsigned short*)(ws + 16 * (1<<20));  // 4 MB (bf16)
  float* AT  = (float*)(ws + 24 * (1<<20));                   // 8 MB
  float* RET = (float*)(ws + 32 * (1<<20));                   // 8 MB (NOT aliased:
                    // ret_o2_k reads AT while writing RET in the same dispatch)
  unsigned short* WT = (unsigned short*)(ws + 40 * (1<<20));  // 2.5 MB
  (void)ws_size;

  // 1) fused cast-x + weight transposes
  prep_k<<<dim3(1024 + 320), 256, 0, stream>>>(x, Xb, WQ, WK, WV, WG, WO, WT);
  // 2) fused projections (stacked N=2048): Qb,Kb,Vb,G all bf16
  mfma_gemm_k<<<dim3(16, M_ROWS / 128), 256, 0, stream>>>(
      Xb, WT, Qb, Kb, Vb, G);
  // 3) chunk KV outer products
  ret_kv_k<<<dim3(T_SEQ / 64, NH, 2), 256, 0, stream>>>(Kb, Vb, AT);
  // 4) fused prefix-scan + retention output
  ret_o2_k<<<dim3(T_SEQ / 64, NH, 2), 256, 0, stream>>>(Qb, Kb, Vb, AT, RET);
  // 5) output projection with fused GroupNorm+SiLU gate
  out_gemm_k<<<dim3(4, M_ROWS / 128), 256, 0, stream>>>(
      RET, G, gnw, gnb, WT + 4 * DMODEL * DMODEL, out);
}

// Round 7
// 130.014 us; speedup vs baseline: 1.1958x; 1.1958x over previous
//
#include <hip/hip_runtime.h>
#include <hip/hip_bf16.h>
#include <math.h>

#define DMODEL 512
#define T_SEQ 2048
#define NH 8
#define DH 64
#define M_ROWS 4096
#define LDST 72   // padded LDS row stride (retention kernels only)

typedef short s16x8 __attribute__((ext_vector_type(8)));
typedef float f32x4 __attribute__((ext_vector_type(4)));

static __device__ __forceinline__ unsigned short f2bf(float f) {
  __hip_bfloat16 h = __float2bfloat16(f);
  return *(unsigned short*)&h;
}
static __device__ __forceinline__ float bf2f(unsigned short u) {
  union { unsigned int i; float f; } x; x.i = (unsigned int)u << 16; return x.f;
}
// async global->LDS 16B copy; LDS dest must be wave-uniform base + lane*16
static __device__ __forceinline__ void gld16(void* lds, const void* g) {
  __builtin_amdgcn_global_load_lds(
      (const __attribute__((address_space(1))) unsigned int*)g,
      (__attribute__((address_space(3))) unsigned int*)lds, 16, 0, 0);
}

// ---------------------------------------------------------------------------
// Fused prep: blocks 0..1023 cast x -> bf16; blocks 1024..1343 transpose+cast
// the 5 weight matrices: WT[z*512 + n][k] = W_z[k][n].
// ---------------------------------------------------------------------------
__global__ __launch_bounds__(256) void prep_k(
    const float* __restrict__ x, unsigned short* __restrict__ Xb,
    const float* __restrict__ W0, const float* __restrict__ W1,
    const float* __restrict__ W2, const float* __restrict__ W3,
    const float* __restrict__ W4, unsigned short* __restrict__ WT)
{
  __shared__ __align__(16) unsigned short buf[64 * LDST];
  const int bid = blockIdx.x, tid = threadIdx.x;
  if (bid < 1024) {
    const size_t i = ((size_t)bid * 256 + tid) * 8;
    float4 a = *(const float4*)&x[i];
    float4 b = *(const float4*)&x[i + 4];
    s16x8 o;
    o[0]=f2bf(a.x); o[1]=f2bf(a.y); o[2]=f2bf(a.z); o[3]=f2bf(a.w);
    o[4]=f2bf(b.x); o[5]=f2bf(b.y); o[6]=f2bf(b.z); o[7]=f2bf(b.w);
    *(s16x8*)&Xb[i] = o;
    return;
  }
  const int bid2 = bid - 1024;
  const int z = bid2 >> 6, rem = bid2 & 63;
  const int n0 = (rem & 7) * 64, k0 = (rem >> 3) * 64;
  const float* W = (z==0)?W0:(z==1)?W1:(z==2)?W2:(z==3)?W3:W4;
  #pragma unroll
  for (int r = 0; r < 4; ++r) {
    int idx = r * 256 + tid;
    int kr = idx >> 4, nc = idx & 15;
    float4 v = *(const float4*)&W[(size_t)(k0 + kr) * DMODEL + n0 + nc * 4];
    buf[(nc*4+0) * LDST + kr] = f2bf(v.x);
    buf[(nc*4+1) * LDST + kr] = f2bf(v.y);
    buf[(nc*4+2) * LDST + kr] = f2bf(v.z);
    buf[(nc*4+3) * LDST + kr] = f2bf(v.w);
  }
  __syncthreads();
  #pragma unroll
  for (int r = 0; r < 2; ++r) {
    int idx = r * 256 + tid;
    int nr = idx >> 3, c = idx & 7;
    *(s16x8*)&WT[((size_t)z * DMODEL + n0 + nr) * DMODEL + k0 + c * 8] =
        *(const s16x8*)&buf[nr * LDST + c * 8];
  }
}

// ---------------------------------------------------------------------------
// Projection GEMM: C = A(4096x512 bf16) @ BT^T, 128x128 tile, BK=64.
// m97-style global_load_lds + XOR chunk swizzle. All outputs bf16.
// ---------------------------------------------------------------------------
__global__ __launch_bounds__(256) void mfma_gemm_k(
    const unsigned short* __restrict__ A, const unsigned short* __restrict__ BT,
    unsigned short* __restrict__ C0, unsigned short* __restrict__ C1,
    unsigned short* __restrict__ C2, unsigned short* __restrict__ C3)
{
  __shared__ __align__(16) unsigned short As[128 * 64];
  __shared__ __align__(16) unsigned short Bs[128 * 64];
  const int ng0 = blockIdx.x * 128;
  const int m0 = blockIdx.y * 128;
  const int z = ng0 >> 9, n0 = ng0 & 511;
  unsigned short* Cz = (z==0)?C0:(z==1)?C1:(z==2)?C2:C3;
  const int tid = threadIdx.x;
  const int wave = tid >> 6, lane = tid & 63;
  const int wm = wave >> 1, wn = wave & 1;
  const int n = lane & 15, quad = lane >> 4;

  int srow[4], scol[4];
  #pragma unroll
  for (int r = 0; r < 4; ++r) {
    int idx = r * 256 + tid;
    srow[r] = idx >> 3;
    scol[r] = ((idx & 7) ^ (srow[r] & 7)) * 8;
  }

  f32x4 acc[4][4];
  #pragma unroll
  for (int mi = 0; mi < 4; ++mi)
    #pragma unroll
    for (int ni = 0; ni < 4; ++ni) acc[mi][ni] = (f32x4){0.f,0.f,0.f,0.f};

  for (int k0 = 0; k0 < 512; k0 += 64) {
    #pragma unroll
    for (int r = 0; r < 4; ++r) {
      int idx = r * 256 + tid;
      gld16(&As[idx * 8], &A[(size_t)(m0 + srow[r]) * DMODEL + k0 + scol[r]]);
      gld16(&Bs[idx * 8], &BT[(size_t)(ng0 + srow[r]) * DMODEL + k0 + scol[r]]);
    }
    __syncthreads();
    #pragma unroll
    for (int kk = 0; kk < 2; ++kk) {
      s16x8 af[4], bf[4];
      #pragma unroll
      for (int mi = 0; mi < 4; ++mi) {
        int R = wm*64 + mi*16 + n, cc = (kk*4 + quad) ^ (n & 7);
        af[mi] = *(const s16x8*)&As[R * 64 + cc * 8];
      }
      #pragma unroll
      for (int ni = 0; ni < 4; ++ni) {
        int R = wn*64 + ni*16 + n, cc = (kk*4 + quad) ^ (n & 7);
        bf[ni] = *(const s16x8*)&Bs[R * 64 + cc * 8];
      }
      #pragma unroll
      for (int mi = 0; mi < 4; ++mi)
        #pragma unroll
        for (int ni = 0; ni < 4; ++ni)
          acc[mi][ni] = __builtin_amdgcn_mfma_f32_16x16x32_bf16(
              af[mi], bf[ni], acc[mi][ni], 0, 0, 0);
    }
    __syncthreads();
  }

  #pragma unroll
  for (int mi = 0; mi < 4; ++mi)
    #pragma unroll
    for (int ni = 0; ni < 4; ++ni)
      #pragma unroll
      for (int r = 0; r < 4; ++r)
        Cz[(size_t)(m0 + wm*64 + mi*16 + quad*4 + r) * DMODEL +
           n0 + wn*64 + ni*16 + n] = f2bf(acc[mi][ni][r]);
}

// ---------------------------------------------------------------------------
// Chunked retention stage 1: AT[bh][c][d2][d1] = sum_m g^(64-m) K[m][d1] V[m][d2]
// ---------------------------------------------------------------------------
__global__ __launch_bounds__(256) void ret_kv_k(
    const unsigned short* __restrict__ Kb, const unsigned short* __restrict__ Vb,
    float* __restrict__ AT)
{
  __shared__ __align__(16) unsigned short Kts[64 * LDST]; // [d1][m], scaled
  __shared__ __align__(16) unsigned short Vts[64 * LDST]; // [d2][m]
  const int c = blockIdx.x, h = blockIdx.y, b = blockIdx.z;
  const int bh = b * NH + h;
  const int tid = threadIdx.x;
  const int wave = tid >> 6, lane = tid & 63;
  const int n = lane & 15, quad = lane >> 4;
  const size_t base = ((size_t)b * T_SEQ + (size_t)c * 64) * DMODEL + h * DH;
  const float lg = log2f(1.0f - exp2f(-5.0f - (float)h));

  #pragma unroll
  for (int r = 0; r < 2; ++r) {
    int idx = r * 256 + tid;
    int m = idx & 63, ch = idx >> 6;
    s16x8 kv = *(const s16x8*)&Kb[base + (size_t)m * DMODEL + ch * 8];
    s16x8 vv = *(const s16x8*)&Vb[base + (size_t)m * DMODEL + ch * 8];
    float sc = exp2f((float)(64 - m) * lg);
    #pragma unroll
    for (int e = 0; e < 8; ++e) {
      Kts[(ch * 8 + e) * LDST + m] = f2bf(bf2f(((unsigned short*)&kv)[e]) * sc);
      Vts[(ch * 8 + e) * LDST + m] = ((unsigned short*)&vv)[e];
    }
  }
  __syncthreads();

  f32x4 at[4];
  #pragma unroll
  for (int j = 0; j < 4; ++j) at[j] = (f32x4){0.f,0.f,0.f,0.f};
  #pragma unroll
  for (int kk = 0; kk < 2; ++kk) {
    s16x8 a = *(const s16x8*)&Vts[(wave*16 + n) * LDST + kk*32 + quad*8];
    #pragma unroll
    for (int j = 0; j < 4; ++j) {
      s16x8 bf = *(const s16x8*)&Kts[(j*16 + n) * LDST + kk*32 + quad*8];
      at[j] = __builtin_amdgcn_mfma_f32_16x16x32_bf16(a, bf, at[j], 0, 0, 0);
    }
  }
  float* Ab = AT + (((size_t)bh * 32 + c) << 12);
  #pragma unroll
  for (int j = 0; j < 4; ++j)
    #pragma unroll
    for (int r = 0; r < 4; ++r)
      Ab[(wave*16 + quad*4 + r) * 64 + j*16 + n] = at[j][r];
}

// ---------------------------------------------------------------------------
// Chunked retention stage 2 (fused scan + output + GroupNorm + gate + SiLU):
//   S_c = Horner prefix of AT over chunks (fp32 regs, 16 elems/thread)
//   O   = diag-tile flash + 0.125*g^i*(Q @ S_c)
//   Sb  = silu(G + gn(O)*gnw + gnb)  -- group == head, tile is the full group
// ---------------------------------------------------------------------------
__global__ __launch_bounds__(256) void ret_o2_k(
    const unsigned short* __restrict__ Qb, const unsigned short* __restrict__ Kb,
    const unsigned short* __restrict__ Vb, const float* __restrict__ AT,
    const unsigned short* __restrict__ Gg, const float* __restrict__ gnw,
    const float* __restrict__ gnb, unsigned short* __restrict__ Sb)
{
  __shared__ __align__(16) unsigned short Qs[64 * LDST];
  __shared__ __align__(16) unsigned short Ks[64 * LDST];
  __shared__ __align__(16) unsigned short Vst[64 * LDST]; // [d2][m]
  __shared__ __align__(16) unsigned short Ss[64 * LDST];  // [d2][d1]
  __shared__ __align__(16) unsigned short Ps[64 * LDST];
  const int c = (int)gridDim.x - 1 - (int)blockIdx.x;     // heavy chunks first
  const int h = blockIdx.y, b = blockIdx.z;
  const int bh = b * NH + h;
  const int tid = threadIdx.x;
  const int wave = tid >> 6, lane = tid & 63;
  const int n = lane & 15, quad = lane >> 4;
  const size_t base = ((size_t)b * T_SEQ + (size_t)c * 64) * DMODEL + h * DH;
  const float lg = log2f(1.0f - exp2f(-5.0f - (float)h));
  const float g64 = exp2f(64.0f * lg);

  // stage Q, K, V tiles
  #pragma unroll
  for (int r = 0; r < 2; ++r) {
    int idx = r * 256 + tid;
    int i = idx >> 3, ch = idx & 7;
    *(s16x8*)&Qs[i * LDST + ch * 8] =
        *(const s16x8*)&Qb[base + (size_t)i * DMODEL + ch * 8];
    *(s16x8*)&Ks[i * LDST + ch * 8] =
        *(const s16x8*)&Kb[base + (size_t)i * DMODEL + ch * 8];
  }
  #pragma unroll
  for (int r = 0; r < 2; ++r) {
    int idx = r * 256 + tid;
    int m = idx & 63, ch = idx >> 6;
    s16x8 vv = *(const s16x8*)&Vb[base + (size_t)m * DMODEL + ch * 8];
    #pragma unroll
    for (int e = 0; e < 8; ++e)
      Vst[(ch * 8 + e) * LDST + m] = ((unsigned short*)&vv)[e];
  }

  // Horner prefix state: S_c = sum_{cp<c} g64^(c-1-cp) * A[cp], 16 elems/thread
  const float* Ac = AT + (((size_t)bh * 32) << 12) + (size_t)tid * 16;
  float4 S0 = {0,0,0,0}, S1 = S0, S2 = S0, S3 = S0;
  if (c > 0) {
    float4 n0 = *(const float4*)(Ac + 0);
    float4 n1 = *(const float4*)(Ac + 4);
    float4 n2 = *(const float4*)(Ac + 8);
    float4 n3 = *(const float4*)(Ac + 12);
    for (int cp = 0; cp < c; ++cp) {
      float4 a0 = n0, a1 = n1, a2 = n2, a3 = n3;
      if (cp + 1 < c) {
        const float* p = Ac + ((size_t)(cp + 1) << 12);
        n0 = *(const float4*)(p + 0);  n1 = *(const float4*)(p + 4);
        n2 = *(const float4*)(p + 8);  n3 = *(const float4*)(p + 12);
      }
      S0.x = fmaf(g64, S0.x, a0.x); S0.y = fmaf(g64, S0.y, a0.y);
      S0.z = fmaf(g64, S0.z, a0.z); S0.w = fmaf(g64, S0.w, a0.w);
      S1.x = fmaf(g64, S1.x, a1.x); S1.y = fmaf(g64, S1.y, a1.y);
      S1.z = fmaf(g64, S1.z, a1.z); S1.w = fmaf(g64, S1.w, a1.w);
      S2.x = fmaf(g64, S2.x, a2.x); S2.y = fmaf(g64, S2.y, a2.y);
      S2.z = fmaf(g64, S2.z, a2.z); S2.w = fmaf(g64, S2.w, a2.w);
      S3.x = fmaf(g64, S3.x, a3.x); S3.y = fmaf(g64, S3.y, a3.y);
      S3.z = fmaf(g64, S3.z, a3.z); S3.w = fmaf(g64, S3.w, a3.w);
    }
  }
  // write S_c (bf16) into Ss: thread's elems are row d2 = tid>>2,
  // cols (tid&3)*16 .. +15
  {
    const int d2 = tid >> 2, d1b = (tid & 3) * 16;
    s16x8 lo, hi;
    lo[0]=f2bf(S0.x); lo[1]=f2bf(S0.y); lo[2]=f2bf(S0.z); lo[3]=f2bf(S0.w);
    lo[4]=f2bf(S1.x); lo[5]=f2bf(S1.y); lo[6]=f2bf(S1.z); lo[7]=f2bf(S1.w);
    hi[0]=f2bf(S2.x); hi[1]=f2bf(S2.y); hi[2]=f2bf(S2.z); hi[3]=f2bf(S2.w);
    hi[4]=f2bf(S3.x); hi[5]=f2bf(S3.y); hi[6]=f2bf(S3.z); hi[7]=f2bf(S3.w);
    *(s16x8*)&Ss[d2 * LDST + d1b] = lo;
    *(s16x8*)&Ss[d2 * LDST + d1b + 8] = hi;
  }
  __syncthreads();

  f32x4 s[4], u[4];
  #pragma unroll
  for (int j = 0; j < 4; ++j) {
    s[j] = (f32x4){0.f,0.f,0.f,0.f};
    u[j] = (f32x4){0.f,0.f,0.f,0.f};
  }
  #pragma unroll
  for (int kk = 0; kk < 2; ++kk) {
    s16x8 a = *(const s16x8*)&Qs[(wave*16 + n) * LDST + kk*32 + quad*8];
    #pragma unroll
    for (int j = 0; j < 4; ++j) {
      s16x8 bk = *(const s16x8*)&Ks[(j*16 + n) * LDST + kk*32 + quad*8];
      s[j] = __builtin_amdgcn_mfma_f32_16x16x32_bf16(a, bk, s[j], 0, 0, 0);
      s16x8 bs = *(const s16x8*)&Ss[(j*16 + n) * LDST + kk*32 + quad*8];
      u[j] = __builtin_amdgcn_mfma_f32_16x16x32_bf16(a, bs, u[j], 0, 0, 0);
    }
  }

  float rowf[4], colf[4];
  #pragma unroll
  for (int r = 0; r < 4; ++r) rowf[r] = exp2f((float)(wave*16 + quad*4 + r) * lg);
  #pragma unroll
  for (int j = 0; j < 4; ++j) colf[j] = exp2f(-(float)(j*16 + n) * lg);

  #pragma unroll
  for (int j = 0; j < 4; ++j)
    #pragma unroll
    for (int r = 0; r < 4; ++r) {
      int i = wave*16 + quad*4 + r, mcol = j*16 + n;
      float v = (mcol <= i) ? s[j][r] * 0.125f * rowf[r] * colf[j] : 0.0f;
      Ps[i * LDST + mcol] = f2bf(v);
    }
  __syncthreads();

  f32x4 acc[4];
  #pragma unroll
  for (int j = 0; j < 4; ++j) acc[j] = (f32x4){0.f,0.f,0.f,0.f};
  #pragma unroll
  for (int kk = 0; kk < 2; ++kk) {
    s16x8 a = *(const s16x8*)&Ps[(wave*16 + n) * LDST + kk*32 + quad*8];
    #pragma unroll
    for (int j = 0; j < 4; ++j) {
      s16x8 bf = *(const s16x8*)&Vst[(j*16 + n) * LDST + kk*32 + quad*8];
      acc[j] = __builtin_amdgcn_mfma_f32_16x16x32_bf16(a, bf, acc[j], 0, 0, 0);
    }
  }

  // full retention output in registers: ov[j][r] for (row i, col j*16+n)
  float ov[4][4];
  #pragma unroll
  for (int j = 0; j < 4; ++j)
    #pragma unroll
    for (int r = 0; r < 4; ++r)
      ov[j][r] = acc[j][r] + 0.125f * rowf[r] * u[j][r];

  // per-lane gn affine params for this head's cols j*16+n
  float gw[4], gb[4];
  #pragma unroll
  for (int j = 0; j < 4; ++j) {
    gw[j] = gnw[h*DH + j*16 + n];
    gb[j] = gnb[h*DH + j*16 + n];
  }

  // fused GroupNorm (group == head, tile holds full group) + gate + SiLU
  #pragma unroll
  for (int r = 0; r < 4; ++r) {
    float sum = ov[0][r] + ov[1][r] + ov[2][r] + ov[3][r];
    float sq  = ov[0][r]*ov[0][r] + ov[1][r]*ov[1][r]
              + ov[2][r]*ov[2][r] + ov[3][r]*ov[3][r];
    #pragma unroll
    for (int off = 8; off > 0; off >>= 1) {  // reduce over 16-lane n-group
      sum += __shfl_xor(sum, off, 64);
      sq  += __shfl_xor(sq,  off, 64);
    }
    const float mean = sum * (1.0f / 64.0f);
    float var = sq * (1.0f / 64.0f) - mean * mean;
    var = fmaxf(var, 0.0f);
    const float rstd = rsqrtf(var + 1e-5f);
    const int i = wave*16 + quad*4 + r;
    const size_t rowoff = base + (size_t)i * DMODEL;  // col base = h*DH
    #pragma unroll
    for (int j = 0; j < 4; ++j) {
      float normed = (ov[j][r] - mean) * rstd * gw[j] + gb[j];
      float uu = bf2f(Gg[rowoff + j*16 + n]) + normed;
      Sb[rowoff + j*16 + n] = f2bf(uu / (1.0f + expf(-uu)));
    }
  }
}

// ---------------------------------------------------------------------------
// Output GEMM: out = Sb(4096x512 bf16) @ WO^T, fp32 store. Plain m97-style.
// ---------------------------------------------------------------------------
__global__ __launch_bounds__(256) void out_gemm_k(
    const unsigned short* __restrict__ A, const unsigned short* __restrict__ BT,
    float* __restrict__ out)
{
  __shared__ __align__(16) unsigned short As[128 * 64];
  __shared__ __align__(16) unsigned short Bs[128 * 64];
  const int n0 = blockIdx.x * 128;
  const int m0 = blockIdx.y * 128;
  const int tid = threadIdx.x;
  const int wave = tid >> 6, lane = tid & 63;
  const int wm = wave >> 1, wn = wave & 1;
  const int n = lane & 15, quad = lane >> 4;

  int srow[4], scol[4];
  #pragma unroll
  for (int r = 0; r < 4; ++r) {
    int idx = r * 256 + tid;
    srow[r] = idx >> 3;
    scol[r] = ((idx & 7) ^ (srow[r] & 7)) * 8;
  }

  f32x4 acc[4][4];
  #pragma unroll
  for (int mi = 0; mi < 4; ++mi)
    #pragma unroll
    for (int ni = 0; ni < 4; ++ni) acc[mi][ni] = (f32x4){0.f,0.f,0.f,0.f};

  for (int k0 = 0; k0 < 512; k0 += 64) {
    #pragma unroll
    for (int r = 0; r < 4; ++r) {
      int idx = r * 256 + tid;
      gld16(&As[idx * 8], &A[(size_t)(m0 + srow[r]) * DMODEL + k0 + scol[r]]);
      gld16(&Bs[idx * 8], &BT[(size_t)(n0 + srow[r]) * DMODEL + k0 + scol[r]]);
    }
    __syncthreads();
    #pragma unroll
    for (int kk = 0; kk < 2; ++kk) {
      s16x8 af[4], bf[4];
      #pragma unroll
      for (int mi = 0; mi < 4; ++mi) {
        int R = wm*64 + mi*16 + n, cc = (kk*4 + quad) ^ (n & 7);
        af[mi] = *(const s16x8*)&As[R * 64 + cc * 8];
      }
      #pragma unroll
      for (int ni = 0; ni < 4; ++ni) {
        int R = wn*64 + ni*16 + n, cc = (kk*4 + quad) ^ (n & 7);
        bf[ni] = *(const s16x8*)&Bs[R * 64 + cc * 8];
      }
      #pragma unroll
      for (int mi = 0; mi < 4; ++mi)
        #pragma unroll
        for (int ni = 0; ni < 4; ++ni)
          acc[mi][ni] = __builtin_amdgcn_mfma_f32_16x16x32_bf16(
              af[mi], bf[ni], acc[mi][ni], 0, 0, 0);
    }
    __syncthreads();
  }

  #pragma unroll
  for (int mi = 0; mi < 4; ++mi)
    #pragma unroll
    for (int ni = 0; ni < 4; ++ni)
      #pragma unroll
      for (int r = 0; r < 4; ++r)
        out[(size_t)(m0 + wm*64 + mi*16 + quad*4 + r) * DMODEL +
            n0 + wn*64 + ni*16 + n] = acc[mi][ni][r];
}

// ---------------------------------------------------------------------------
extern "C" void kernel_launch(void* const* d_in, const int* in_sizes, int n_in,
                              void* d_out, int out_size, void* d_ws, size_t ws_size,
                              hipStream_t stream) {
  const float* x   = (const float*)d_in[0];
  const float* WQ  = (const float*)d_in[1];
  const float* WK  = (const float*)d_in[2];
  const float* WV  = (const float*)d_in[3];
  const float* WG  = (const float*)d_in[4];
  const float* WO  = (const float*)d_in[5];
  const float* gnw = (const float*)d_in[6];
  const float* gnb = (const float*)d_in[7];
  float* out = (float*)d_out;

  char* ws = (char*)d_ws;
  unsigned short* Xb = (unsigned short*)(ws);                 // 4 MB
  unsigned short* Qb = (unsigned short*)(ws + 4  * (1<<20));  // 4 MB
  unsigned short* Kb = (unsigned short*)(ws + 8  * (1<<20));  // 4 MB
  unsigned short* Vb = (unsigned short*)(ws + 12 * (1<<20));  // 4 MB
  unsigned short* G  = (unsigned short*)(ws + 16 * (1<<20));  // 4 MB (bf16)
  float* AT  = (float*)(ws + 24 * (1<<20));                   // 8 MB
  unsigned short* Sb = (unsigned short*)(ws + 32 * (1<<20));  // 4 MB
  unsigned short* WT = (unsigned short*)(ws + 40 * (1<<20));  // 2.5 MB
  (void)ws_size;

  // 1) fused cast-x + weight transposes
  prep_k<<<dim3(1024 + 320), 256, 0, stream>>>(x, Xb, WQ, WK, WV, WG, WO, WT);
  // 2) fused projections (stacked N=2048): Qb,Kb,Vb,G all bf16
  mfma_gemm_k<<<dim3(16, M_ROWS / 128), 256, 0, stream>>>(
      Xb, WT, Qb, Kb, Vb, G);
  // 3) chunk KV outer products
  ret_kv_k<<<dim3(T_SEQ / 64, NH, 2), 256, 0, stream>>>(Kb, Vb, AT);
  // 4) fused prefix-scan + retention output + GroupNorm + gate + SiLU
  ret_o2_k<<<dim3(T_SEQ / 64, NH, 2), 256, 0, stream>>>(
      Qb, Kb, Vb, AT, G, gnw, gnb, Sb);
  // 5) output projection (fp32 out)
  out_gemm_k<<<dim3(4, M_ROWS / 128), 256, 0, stream>>>(
      Sb, WT + 4 * DMODEL * DMODEL, out);
}

// Round 8
// 125.541 us; speedup vs baseline: 1.2384x; 1.0356x over previous
//
#include <hip/hip_runtime.h>
#include <hip/hip_bf16.h>
#include <math.h>

#define DMODEL 512
#define T_SEQ 2048
#define NH 8
#define DH 64
#define M_ROWS 4096
#define LDST 72   // padded LDS row stride (retention/epilogue staging)

typedef short s16x8 __attribute__((ext_vector_type(8)));
typedef float f32x4 __attribute__((ext_vector_type(4)));

static __device__ __forceinline__ unsigned short f2bf(float f) {
  __hip_bfloat16 h = __float2bfloat16(f);
  return *(unsigned short*)&h;
}
static __device__ __forceinline__ float bf2f(unsigned short u) {
  union { unsigned int i; float f; } x; x.i = (unsigned int)u << 16; return x.f;
}
// async global->LDS 16B copy; LDS dest must be wave-uniform base + lane*16
static __device__ __forceinline__ void gld16(void* lds, const void* g) {
  __builtin_amdgcn_global_load_lds(
      (const __attribute__((address_space(1))) unsigned int*)g,
      (__attribute__((address_space(3))) unsigned int*)lds, 16, 0, 0);
}

// ---------------------------------------------------------------------------
// Fused prep: blocks 0..1023 cast x -> bf16; blocks 1024..1343 transpose+cast
// the 5 weight matrices into the stacked-row layout:
//   rows    0..511  : W_Q cols (d-major)
//   rows  512..1535 : per-head interleave [K_h(64) | V_h(64)] x 8 heads
//   rows 1536..2047 : W_G cols
//   rows 2048..2559 : W_O cols
// ---------------------------------------------------------------------------
__global__ __launch_bounds__(256) void prep_k(
    const float* __restrict__ x, unsigned short* __restrict__ Xb,
    const float* __restrict__ W0, const float* __restrict__ W1,
    const float* __restrict__ W2, const float* __restrict__ W3,
    const float* __restrict__ W4, unsigned short* __restrict__ WT)
{
  __shared__ __align__(16) unsigned short buf[64 * LDST];
  const int bid = blockIdx.x, tid = threadIdx.x;
  if (bid < 1024) {
    const size_t i = ((size_t)bid * 256 + tid) * 8;
    float4 a = *(const float4*)&x[i];
    float4 b = *(const float4*)&x[i + 4];
    s16x8 o;
    o[0]=f2bf(a.x); o[1]=f2bf(a.y); o[2]=f2bf(a.z); o[3]=f2bf(a.w);
    o[4]=f2bf(b.x); o[5]=f2bf(b.y); o[6]=f2bf(b.z); o[7]=f2bf(b.w);
    *(s16x8*)&Xb[i] = o;
    return;
  }
  const int bid2 = bid - 1024;
  const int z = bid2 >> 6, rem = bid2 & 63;
  const int n0 = (rem & 7) * 64, k0 = (rem >> 3) * 64;
  const float* W = (z==0)?W0:(z==1)?W1:(z==2)?W2:(z==3)?W3:W4;
  int rowbase;
  if (z == 0)      rowbase = n0;
  else if (z == 1) rowbase = 512 + (n0 >> 6) * 128;        // K_h block
  else if (z == 2) rowbase = 512 + (n0 >> 6) * 128 + 64;   // V_h block
  else if (z == 3) rowbase = 1536 + n0;
  else             rowbase = 2048 + n0;
  #pragma unroll
  for (int r = 0; r < 4; ++r) {
    int idx = r * 256 + tid;
    int kr = idx >> 4, nc = idx & 15;
    float4 v = *(const float4*)&W[(size_t)(k0 + kr) * DMODEL + n0 + nc * 4];
    buf[(nc*4+0) * LDST + kr] = f2bf(v.x);
    buf[(nc*4+1) * LDST + kr] = f2bf(v.y);
    buf[(nc*4+2) * LDST + kr] = f2bf(v.z);
    buf[(nc*4+3) * LDST + kr] = f2bf(v.w);
  }
  __syncthreads();
  #pragma unroll
  for (int r = 0; r < 2; ++r) {
    int idx = r * 256 + tid;
    int nr = idx >> 3, c = idx & 7;
    *(s16x8*)&WT[((size_t)(rowbase + nr)) * DMODEL + k0 + c * 8] =
        *(const s16x8*)&buf[nr * LDST + c * 8];
  }
}

// ---------------------------------------------------------------------------
// Projection GEMM + fused KV outer product.
// C = Xb(4096x512) @ WT^T over stacked rows 0..2047; 128x128 tile, BK=64.
// Tiles 0-3: Q -> Qb. Tiles 4-11: [K_h|V_h] -> Kb/Vb PLUS in-register
// AT[bh][c][d2][d1] = sum_m g^(64-m) K[m][d1] V[m][d2] (2 chunks per block).
// Tiles 12-15: G -> Gb.
// ---------------------------------------------------------------------------
__global__ __launch_bounds__(256) void proj_kv_k(
    const unsigned short* __restrict__ A, const unsigned short* __restrict__ BT,
    unsigned short* __restrict__ Qb, unsigned short* __restrict__ Kb,
    unsigned short* __restrict__ Vb, unsigned short* __restrict__ Gb,
    float* __restrict__ AT)
{
  __shared__ __align__(16) unsigned short smem[2 * 128 * 64];
  unsigned short* As = smem;
  unsigned short* Bs = smem + 128 * 64;
  const int ng0 = blockIdx.x * 128;
  const int m0 = blockIdx.y * 128;
  const int tid = threadIdx.x;
  const int wave = tid >> 6, lane = tid & 63;
  const int wm = wave >> 1, wn = wave & 1;
  const int n = lane & 15, quad = lane >> 4;

  int srow[4], scol[4];
  #pragma unroll
  for (int r = 0; r < 4; ++r) {
    int idx = r * 256 + tid;
    srow[r] = idx >> 3;
    scol[r] = ((idx & 7) ^ (srow[r] & 7)) * 8;
  }

  f32x4 acc[4][4];
  #pragma unroll
  for (int mi = 0; mi < 4; ++mi)
    #pragma unroll
    for (int ni = 0; ni < 4; ++ni) acc[mi][ni] = (f32x4){0.f,0.f,0.f,0.f};

  for (int k0 = 0; k0 < 512; k0 += 64) {
    #pragma unroll
    for (int r = 0; r < 4; ++r) {
      int idx = r * 256 + tid;
      gld16(&As[idx * 8], &A[(size_t)(m0 + srow[r]) * DMODEL + k0 + scol[r]]);
      gld16(&Bs[idx * 8], &BT[(size_t)(ng0 + srow[r]) * DMODEL + k0 + scol[r]]);
    }
    __syncthreads();
    #pragma unroll
    for (int kk = 0; kk < 2; ++kk) {
      s16x8 af[4], bf[4];
      #pragma unroll
      for (int mi = 0; mi < 4; ++mi) {
        int R = wm*64 + mi*16 + n, cc = (kk*4 + quad) ^ (n & 7);
        af[mi] = *(const s16x8*)&As[R * 64 + cc * 8];
      }
      #pragma unroll
      for (int ni = 0; ni < 4; ++ni) {
        int R = wn*64 + ni*16 + n, cc = (kk*4 + quad) ^ (n & 7);
        bf[ni] = *(const s16x8*)&Bs[R * 64 + cc * 8];
      }
      #pragma unroll
      for (int mi = 0; mi < 4; ++mi)
        #pragma unroll
        for (int ni = 0; ni < 4; ++ni)
          acc[mi][ni] = __builtin_amdgcn_mfma_f32_16x16x32_bf16(
              af[mi], bf[ni], acc[mi][ni], 0, 0, 0);
    }
    __syncthreads();
  }

  const int bx = blockIdx.x;
  if (bx < 4 || bx >= 12) {
    // plain Q / G slab
    unsigned short* Cz = (bx < 4) ? Qb : Gb;
    const int n0 = (bx < 4) ? ng0 : (ng0 - 1536);
    #pragma unroll
    for (int mi = 0; mi < 4; ++mi)
      #pragma unroll
      for (int ni = 0; ni < 4; ++ni)
        #pragma unroll
        for (int r = 0; r < 4; ++r)
          Cz[(size_t)(m0 + wm*64 + mi*16 + quad*4 + r) * DMODEL +
             n0 + wn*64 + ni*16 + n] = f2bf(acc[mi][ni][r]);
    return;
  }

  // KV tile: head h, cols 0..63 = K_h (wn==0), 64..127 = V_h (wn==1)
  const int h = (ng0 - 512) >> 7;
  const float lg = log2f(1.0f - exp2f(-5.0f - (float)h));
  unsigned short* KVo = (wn == 0) ? Kb : Vb;
  #pragma unroll
  for (int mi = 0; mi < 4; ++mi)
    #pragma unroll
    for (int ni = 0; ni < 4; ++ni)
      #pragma unroll
      for (int r = 0; r < 4; ++r)
        KVo[(size_t)(m0 + wm*64 + mi*16 + quad*4 + r) * DMODEL +
            h*DH + ni*16 + n] = f2bf(acc[mi][ni][r]);

  // fused AT: per 64-row chunk, stage scaled K^T and V^T, 8 MFMAs, store
  unsigned short* Kt = smem;                 // [d1][m], LDST stride
  unsigned short* Vt = smem + 64 * LDST;
  #pragma unroll
  for (int cc2 = 0; cc2 < 2; ++cc2) {
    __syncthreads();   // staging buffers free / previous chunk's MFMA done
    if (wm == cc2) {
      unsigned short* Tt = (wn == 0) ? Kt : Vt;
      #pragma unroll
      for (int mi = 0; mi < 4; ++mi)
        #pragma unroll
        for (int r = 0; r < 4; ++r) {
          int m = mi*16 + quad*4 + r;
          float sc = (wn == 0) ? exp2f((float)(64 - m) * lg) : 1.0f;
          #pragma unroll
          for (int ni = 0; ni < 4; ++ni)
            Tt[(ni*16 + n) * LDST + m] = f2bf(acc[mi][ni][r] * sc);
        }
    }
    __syncthreads();
    f32x4 at[4];
    #pragma unroll
    for (int j = 0; j < 4; ++j) at[j] = (f32x4){0.f,0.f,0.f,0.f};
    #pragma unroll
    for (int kk = 0; kk < 2; ++kk) {
      s16x8 a = *(const s16x8*)&Vt[(wave*16 + n) * LDST + kk*32 + quad*8];
      #pragma unroll
      for (int j = 0; j < 4; ++j) {
        s16x8 bf = *(const s16x8*)&Kt[(j*16 + n) * LDST + kk*32 + quad*8];
        at[j] = __builtin_amdgcn_mfma_f32_16x16x32_bf16(a, bf, at[j], 0, 0, 0);
      }
    }
    const int gr = m0 + cc2 * 64;
    const int bb = gr >> 11, cchunk = (gr & 2047) >> 6;
    float* Ab = AT + (((size_t)(bb * NH + h) * 32 + cchunk) << 12);
    #pragma unroll
    for (int j = 0; j < 4; ++j)
      #pragma unroll
      for (int r = 0; r < 4; ++r)
        Ab[(wave*16 + quad*4 + r) * 64 + j*16 + n] = at[j][r];
  }
}

// ---------------------------------------------------------------------------
// Fused scan + retention output + GroupNorm + gate + SiLU (unchanged, R7).
// ---------------------------------------------------------------------------
__global__ __launch_bounds__(256) void ret_o2_k(
    const unsigned short* __restrict__ Qb, const unsigned short* __restrict__ Kb,
    const unsigned short* __restrict__ Vb, const float* __restrict__ AT,
    const unsigned short* __restrict__ Gg, const float* __restrict__ gnw,
    const float* __restrict__ gnb, unsigned short* __restrict__ Sb)
{
  __shared__ __align__(16) unsigned short Qs[64 * LDST];
  __shared__ __align__(16) unsigned short Ks[64 * LDST];
  __shared__ __align__(16) unsigned short Vst[64 * LDST]; // [d2][m]
  __shared__ __align__(16) unsigned short Ss[64 * LDST];  // [d2][d1]
  __shared__ __align__(16) unsigned short Ps[64 * LDST];
  const int c = (int)gridDim.x - 1 - (int)blockIdx.x;     // heavy chunks first
  const int h = blockIdx.y, b = blockIdx.z;
  const int bh = b * NH + h;
  const int tid = threadIdx.x;
  const int wave = tid >> 6, lane = tid & 63;
  const int n = lane & 15, quad = lane >> 4;
  const size_t base = ((size_t)b * T_SEQ + (size_t)c * 64) * DMODEL + h * DH;
  const float lg = log2f(1.0f - exp2f(-5.0f - (float)h));
  const float g64 = exp2f(64.0f * lg);

  #pragma unroll
  for (int r = 0; r < 2; ++r) {
    int idx = r * 256 + tid;
    int i = idx >> 3, ch = idx & 7;
    *(s16x8*)&Qs[i * LDST + ch * 8] =
        *(const s16x8*)&Qb[base + (size_t)i * DMODEL + ch * 8];
    *(s16x8*)&Ks[i * LDST + ch * 8] =
        *(const s16x8*)&Kb[base + (size_t)i * DMODEL + ch * 8];
  }
  #pragma unroll
  for (int r = 0; r < 2; ++r) {
    int idx = r * 256 + tid;
    int m = idx & 63, ch = idx >> 6;
    s16x8 vv = *(const s16x8*)&Vb[base + (size_t)m * DMODEL + ch * 8];
    #pragma unroll
    for (int e = 0; e < 8; ++e)
      Vst[(ch * 8 + e) * LDST + m] = ((unsigned short*)&vv)[e];
  }

  const float* Ac = AT + (((size_t)bh * 32) << 12) + (size_t)tid * 16;
  float4 S0 = {0,0,0,0}, S1 = S0, S2 = S0, S3 = S0;
  if (c > 0) {
    float4 n0 = *(const float4*)(Ac + 0);
    float4 n1 = *(const float4*)(Ac + 4);
    float4 n2 = *(const float4*)(Ac + 8);
    float4 n3 = *(const float4*)(Ac + 12);
    for (int cp = 0; cp < c; ++cp) {
      float4 a0 = n0, a1 = n1, a2 = n2, a3 = n3;
      if (cp + 1 < c) {
        const float* p = Ac + ((size_t)(cp + 1) << 12);
        n0 = *(const float4*)(p + 0);  n1 = *(const float4*)(p + 4);
        n2 = *(const float4*)(p + 8);  n3 = *(const float4*)(p + 12);
      }
      S0.x = fmaf(g64, S0.x, a0.x); S0.y = fmaf(g64, S0.y, a0.y);
      S0.z = fmaf(g64, S0.z, a0.z); S0.w = fmaf(g64, S0.w, a0.w);
      S1.x = fmaf(g64, S1.x, a1.x); S1.y = fmaf(g64, S1.y, a1.y);
      S1.z = fmaf(g64, S1.z, a1.z); S1.w = fmaf(g64, S1.w, a1.w);
      S2.x = fmaf(g64, S2.x, a2.x); S2.y = fmaf(g64, S2.y, a2.y);
      S2.z = fmaf(g64, S2.z, a2.z); S2.w = fmaf(g64, S2.w, a2.w);
      S3.x = fmaf(g64, S3.x, a3.x); S3.y = fmaf(g64, S3.y, a3.y);
      S3.z = fmaf(g64, S3.z, a3.z); S3.w = fmaf(g64, S3.w, a3.w);
    }
  }
  {
    const int d2 = tid >> 2, d1b = (tid & 3) * 16;
    s16x8 lo, hi;
    lo[0]=f2bf(S0.x); lo[1]=f2bf(S0.y); lo[2]=f2bf(S0.z); lo[3]=f2bf(S0.w);
    lo[4]=f2bf(S1.x); lo[5]=f2bf(S1.y); lo[6]=f2bf(S1.z); lo[7]=f2bf(S1.w);
    hi[0]=f2bf(S2.x); hi[1]=f2bf(S2.y); hi[2]=f2bf(S2.z); hi[3]=f2bf(S2.w);
    hi[4]=f2bf(S3.x); hi[5]=f2bf(S3.y); hi[6]=f2bf(S3.z); hi[7]=f2bf(S3.w);
    *(s16x8*)&Ss[d2 * LDST + d1b] = lo;
    *(s16x8*)&Ss[d2 * LDST + d1b + 8] = hi;
  }
  __syncthreads();

  f32x4 s[4], u[4];
  #pragma unroll
  for (int j = 0; j < 4; ++j) {
    s[j] = (f32x4){0.f,0.f,0.f,0.f};
    u[j] = (f32x4){0.f,0.f,0.f,0.f};
  }
  #pragma unroll
  for (int kk = 0; kk < 2; ++kk) {
    s16x8 a = *(const s16x8*)&Qs[(wave*16 + n) * LDST + kk*32 + quad*8];
    #pragma unroll
    for (int j = 0; j < 4; ++j) {
      s16x8 bk = *(const s16x8*)&Ks[(j*16 + n) * LDST + kk*32 + quad*8];
      s[j] = __builtin_amdgcn_mfma_f32_16x16x32_bf16(a, bk, s[j], 0, 0, 0);
      s16x8 bs = *(const s16x8*)&Ss[(j*16 + n) * LDST + kk*32 + quad*8];
      u[j] = __builtin_amdgcn_mfma_f32_16x16x32_bf16(a, bs, u[j], 0, 0, 0);
    }
  }

  float rowf[4], colf[4];
  #pragma unroll
  for (int r = 0; r < 4; ++r) rowf[r] = exp2f((float)(wave*16 + quad*4 + r) * lg);
  #pragma unroll
  for (int j = 0; j < 4; ++j) colf[j] = exp2f(-(float)(j*16 + n) * lg);

  #pragma unroll
  for (int j = 0; j < 4; ++j)
    #pragma unroll
    for (int r = 0; r < 4; ++r) {
      int i = wave*16 + quad*4 + r, mcol = j*16 + n;
      float v = (mcol <= i) ? s[j][r] * 0.125f * rowf[r] * colf[j] : 0.0f;
      Ps[i * LDST + mcol] = f2bf(v);
    }
  __syncthreads();

  f32x4 acc[4];
  #pragma unroll
  for (int j = 0; j < 4; ++j) acc[j] = (f32x4){0.f,0.f,0.f,0.f};
  #pragma unroll
  for (int kk = 0; kk < 2; ++kk) {
    s16x8 a = *(const s16x8*)&Ps[(wave*16 + n) * LDST + kk*32 + quad*8];
    #pragma unroll
    for (int j = 0; j < 4; ++j) {
      s16x8 bf = *(const s16x8*)&Vst[(j*16 + n) * LDST + kk*32 + quad*8];
      acc[j] = __builtin_amdgcn_mfma_f32_16x16x32_bf16(a, bf, acc[j], 0, 0, 0);
    }
  }

  float ov[4][4];
  #pragma unroll
  for (int j = 0; j < 4; ++j)
    #pragma unroll
    for (int r = 0; r < 4; ++r)
      ov[j][r] = acc[j][r] + 0.125f * rowf[r] * u[j][r];

  float gw[4], gb[4];
  #pragma unroll
  for (int j = 0; j < 4; ++j) {
    gw[j] = gnw[h*DH + j*16 + n];
    gb[j] = gnb[h*DH + j*16 + n];
  }

  #pragma unroll
  for (int r = 0; r < 4; ++r) {
    float sum = ov[0][r] + ov[1][r] + ov[2][r] + ov[3][r];
    float sq  = ov[0][r]*ov[0][r] + ov[1][r]*ov[1][r]
              + ov[2][r]*ov[2][r] + ov[3][r]*ov[3][r];
    #pragma unroll
    for (int off = 8; off > 0; off >>= 1) {
      sum += __shfl_xor(sum, off, 64);
      sq  += __shfl_xor(sq,  off, 64);
    }
    const float mean = sum * (1.0f / 64.0f);
    float var = sq * (1.0f / 64.0f) - mean * mean;
    var = fmaxf(var, 0.0f);
    const float rstd = rsqrtf(var + 1e-5f);
    const size_t rowoff = base + (size_t)(wave*16 + quad*4 + r) * DMODEL;
    #pragma unroll
    for (int j = 0; j < 4; ++j) {
      float normed = (ov[j][r] - mean) * rstd * gw[j] + gb[j];
      float uu = bf2f(Gg[rowoff + j*16 + n]) + normed;
      Sb[rowoff + j*16 + n] = f2bf(uu / (1.0f + expf(-uu)));
    }
  }
}

// ---------------------------------------------------------------------------
// Output GEMM: out = Sb(4096x512 bf16) @ WO^T, fp32. 128x64 tile -> 256 blocks.
// ---------------------------------------------------------------------------
__global__ __launch_bounds__(256) void out_gemm_k(
    const unsigned short* __restrict__ A, const unsigned short* __restrict__ BT,
    float* __restrict__ out)
{
  __shared__ __align__(16) unsigned short As[128 * 64];
  __shared__ __align__(16) unsigned short Bs[64 * 64];
  const int n0 = blockIdx.x * 64;
  const int m0 = blockIdx.y * 128;
  const int tid = threadIdx.x;
  const int wave = tid >> 6, lane = tid & 63;
  const int wm = wave >> 1, wn = wave & 1;
  const int n = lane & 15, quad = lane >> 4;

  int srow[4], scol[4];
  #pragma unroll
  for (int r = 0; r < 4; ++r) {
    int idx = r * 256 + tid;
    srow[r] = idx >> 3;
    scol[r] = ((idx & 7) ^ (srow[r] & 7)) * 8;
  }

  f32x4 acc[4][2];
  #pragma unroll
  for (int mi = 0; mi < 4; ++mi)
    #pragma unroll
    for (int ni = 0; ni < 2; ++ni) acc[mi][ni] = (f32x4){0.f,0.f,0.f,0.f};

  for (int k0 = 0; k0 < 512; k0 += 64) {
    #pragma unroll
    for (int r = 0; r < 4; ++r) {
      int idx = r * 256 + tid;
      gld16(&As[idx * 8], &A[(size_t)(m0 + srow[r]) * DMODEL + k0 + scol[r]]);
    }
    #pragma unroll
    for (int r = 0; r < 2; ++r) {
      int idx = r * 256 + tid;
      gld16(&Bs[idx * 8], &BT[(size_t)(n0 + srow[r]) * DMODEL + k0 + scol[r]]);
    }
    __syncthreads();
    #pragma unroll
    for (int kk = 0; kk < 2; ++kk) {
      s16x8 af[4], bf[2];
      #pragma unroll
      for (int mi = 0; mi < 4; ++mi) {
        int R = wm*64 + mi*16 + n, cc = (kk*4 + quad) ^ (n & 7);
        af[mi] = *(const s16x8*)&As[R * 64 + cc * 8];
      }
      #pragma unroll
      for (int ni = 0; ni < 2; ++ni) {
        int R = wn*32 + ni*16 + n, cc = (kk*4 + quad) ^ (n & 7);
        bf[ni] = *(const s16x8*)&Bs[R * 64 + cc * 8];
      }
      #pragma unroll
      for (int mi = 0; mi < 4; ++mi)
        #pragma unroll
        for (int ni = 0; ni < 2; ++ni)
          acc[mi][ni] = __builtin_amdgcn_mfma_f32_16x16x32_bf16(
              af[mi], bf[ni], acc[mi][ni], 0, 0, 0);
    }
    __syncthreads();
  }

  #pragma unroll
  for (int mi = 0; mi < 4; ++mi)
    #pragma unroll
    for (int ni = 0; ni < 2; ++ni)
      #pragma unroll
      for (int r = 0; r < 4; ++r)
        out[(size_t)(m0 + wm*64 + mi*16 + quad*4 + r) * DMODEL +
            n0 + wn*32 + ni*16 + n] = acc[mi][ni][r];
}

// ---------------------------------------------------------------------------
extern "C" void kernel_launch(void* const* d_in, const int* in_sizes, int n_in,
                              void* d_out, int out_size, void* d_ws, size_t ws_size,
                              hipStream_t stream) {
  const float* x   = (const float*)d_in[0];
  const float* WQ  = (const float*)d_in[1];
  const float* WK  = (const float*)d_in[2];
  const float* WV  = (const float*)d_in[3];
  const float* WG  = (const float*)d_in[4];
  const float* WO  = (const float*)d_in[5];
  const float* gnw = (const float*)d_in[6];
  const float* gnb = (const float*)d_in[7];
  float* out = (float*)d_out;

  char* ws = (char*)d_ws;
  unsigned short* Xb = (unsigned short*)(ws);                 // 4 MB
  unsigned short* Qb = (unsigned short*)(ws + 4  * (1<<20));  // 4 MB
  unsigned short* Kb = (unsigned short*)(ws + 8  * (1<<20));  // 4 MB
  unsigned short* Vb = (unsigned short*)(ws + 12 * (1<<20));  // 4 MB
  unsigned short* G  = (unsigned short*)(ws + 16 * (1<<20));  // 4 MB (bf16)
  float* AT  = (float*)(ws + 24 * (1<<20));                   // 8 MB
  unsigned short* Sb = (unsigned short*)(ws + 32 * (1<<20));  // 4 MB
  unsigned short* WT = (unsigned short*)(ws + 40 * (1<<20));  // 2.5 MB
  (void)ws_size;

  // 1) fused cast-x + weight transpose/stacking
  prep_k<<<dim3(1024 + 320), 256, 0, stream>>>(x, Xb, WQ, WK, WV, WG, WO, WT);
  // 2) projections + fused per-chunk KV outer products
  proj_kv_k<<<dim3(16, M_ROWS / 128), 256, 0, stream>>>(
      Xb, WT, Qb, Kb, Vb, G, AT);
  // 3) fused prefix-scan + retention output + GroupNorm + gate + SiLU
  ret_o2_k<<<dim3(T_SEQ / 64, NH, 2), 256, 0, stream>>>(
      Qb, Kb, Vb, AT, G, gnw, gnb, Sb);
  // 4) output projection (fp32 out), 256 blocks
  out_gemm_k<<<dim3(8, M_ROWS / 128), 256, 0, stream>>>(
      Sb, WT + 2048 * DMODEL, out);
}